// Round 3
// baseline (2270.196 us; speedup 1.0000x reference)
//
#include <hip/hip_runtime.h>
#include <hip/hip_bf16.h>
#include <stdint.h>

#define B_   64
#define S_   512
#define IN_  256
#define H_   512
#define O_   256

// k_rnn W_hh residency split (64 k-groups of 8 cols each):
//   RG in VGPRs (x2 rows/thread), LG in LDS, SG streamed from L2 each step.
#define RG 42
#define LG 18
#define SG 4

typedef _Float16 h16;
typedef __attribute__((ext_vector_type(2))) _Float16 half2v;

static __device__ __forceinline__ float fdot2(uint32_t w, uint32_t h, float acc) {
#if __has_builtin(__builtin_amdgcn_fdot2)
  return __builtin_amdgcn_fdot2(__builtin_bit_cast(half2v, w),
                                __builtin_bit_cast(half2v, h), acc, false);
#else
  half2v a = __builtin_bit_cast(half2v, w), b = __builtin_bit_cast(half2v, h);
  return acc + (float)a[0] * (float)b[0] + (float)a[1] * (float)b[1];
#endif
}

static __device__ __forceinline__ uint32_t pack2(float a, float b) {
  h16 lo = (h16)a, hi = (h16)b;
  uint32_t u = (uint32_t)__builtin_bit_cast(unsigned short, lo);
  uint32_t v = (uint32_t)__builtin_bit_cast(unsigned short, hi);
  return u | (v << 16);
}

static __device__ __forceinline__ float fast_tanh(float x) {
#if __has_builtin(__builtin_amdgcn_exp2f) && __has_builtin(__builtin_amdgcn_rcpf)
  float xc = fminf(9.0f, fmaxf(-9.0f, x));
  float e2 = __builtin_amdgcn_exp2f(xc * 2.8853900817779268f);  // e^{2x}
  return (e2 - 1.0f) * __builtin_amdgcn_rcpf(e2 + 1.0f);
#else
  return tanhf(x);
#endif
}

// ---------------- packing kernels (f32 -> f16x2 dwords) ----------------

__global__ void k_pack_x(const float2* __restrict__ x2, uint32_t* __restrict__ xpk, int n) {
  int i = blockIdx.x * blockDim.x + threadIdx.x;
  int stride = gridDim.x * blockDim.x;
  for (; i < n; i += stride) { float2 v = x2[i]; xpk[i] = pack2(v.x, v.y); }
}

// W_ih (H,IN) -> [k2][n] dwords
__global__ void k_pack_wih(const float* __restrict__ w, uint32_t* __restrict__ wp) {
  int i = blockIdx.x * 256 + threadIdx.x;   // 65536
  int k2 = i >> 9, n = i & 511;
  wp[i] = pack2(w[n * IN_ + 2 * k2], w[n * IN_ + 2 * k2 + 1]);
}

// W_ff (O,H) -> [k2][o] dwords
__global__ void k_pack_wff(const float* __restrict__ w, uint32_t* __restrict__ wp) {
  int i = blockIdx.x * 256 + threadIdx.x;   // 65536
  int k2 = i >> 8, o = i & 255;
  wp[i] = pack2(w[o * H_ + 2 * k2], w[o * H_ + 2 * k2 + 1]);
}

// W_hh (H,H) -> uint4 quads: [g][o], g=k/8 in [0,64), o in [0,512)
__global__ void k_pack_whh(const float* __restrict__ w, uint32_t* __restrict__ wp) {
  int i = blockIdx.x * 256 + threadIdx.x;   // 131072 dwords
  int g = i >> 11, o = (i >> 2) & 511, c = i & 3;
  int k = 8 * g + 2 * c;
  wp[i] = pack2(w[o * H_ + k], w[o * H_ + k + 1]);
}

// ---------------- tiled fdot2 GEMM:  out[M][N] = A[M][K] * W[N][K]^T + bias ----

template <int NSTAGES, bool OUT16>
__global__ void __launch_bounds__(256) k_gemm(
    const uint32_t* __restrict__ apack, const uint32_t* __restrict__ wpack,
    const float* __restrict__ bias0, const float* __restrict__ bias1,
    void* __restrict__ outp, int Ncols)
{
  const int K2 = NSTAGES * 64;
  __shared__ uint32_t xs[128][65];
  __shared__ uint32_t ws[64][64];
  const int tid = threadIdx.x;
  const int mbase = blockIdx.x * 128;
  const int nbase = blockIdx.y * 64;
  const int tx = tid & 7, ty = tid >> 3;
  const int m0 = ty * 4, n0 = tx * 8;

  float bs[8];
#pragma unroll
  for (int j = 0; j < 8; ++j) {
    int n = nbase + n0 + j;
    bs[j] = bias0[n] + (bias1 ? bias1[n] : 0.0f);
  }

  float acc[4][8];
#pragma unroll
  for (int i = 0; i < 4; ++i)
#pragma unroll
    for (int j = 0; j < 8; ++j) acc[i][j] = 0.0f;

  for (int s = 0; s < NSTAGES; ++s) {
    const int k2b = s * 64;
    __syncthreads();
#pragma unroll
    for (int c = 0; c < 32; ++c) {
      int idx = c * 256 + tid;
      int m = idx >> 6, k2 = idx & 63;
      xs[m][k2] = apack[(size_t)(mbase + m) * K2 + k2b + k2];
    }
#pragma unroll
    for (int c = 0; c < 16; ++c) {
      int idx = c * 256 + tid;
      int k2 = idx >> 6, n = idx & 63;
      ws[k2][n] = wpack[(size_t)(k2b + k2) * Ncols + nbase + n];
    }
    __syncthreads();
#pragma unroll 8
    for (int k2 = 0; k2 < 64; ++k2) {
      uint32_t xv[4];
#pragma unroll
      for (int i = 0; i < 4; ++i) xv[i] = xs[m0 + i][k2];
      uint4 wA = *(const uint4*)&ws[k2][n0];
      uint4 wB = *(const uint4*)&ws[k2][n0 + 4];
#pragma unroll
      for (int i = 0; i < 4; ++i) {
        acc[i][0] = fdot2(xv[i], wA.x, acc[i][0]);
        acc[i][1] = fdot2(xv[i], wA.y, acc[i][1]);
        acc[i][2] = fdot2(xv[i], wA.z, acc[i][2]);
        acc[i][3] = fdot2(xv[i], wA.w, acc[i][3]);
        acc[i][4] = fdot2(xv[i], wB.x, acc[i][4]);
        acc[i][5] = fdot2(xv[i], wB.y, acc[i][5]);
        acc[i][6] = fdot2(xv[i], wB.z, acc[i][6]);
        acc[i][7] = fdot2(xv[i], wB.w, acc[i][7]);
      }
    }
  }
  if constexpr (OUT16) {
    uint32_t* o16 = (uint32_t*)outp;
    const int ncd = Ncols >> 1;
#pragma unroll
    for (int i = 0; i < 4; ++i) {
      size_t row = (size_t)(mbase + m0 + i) * ncd + ((nbase + n0) >> 1);
      uint4 pk;
      pk.x = pack2(acc[i][0] + bs[0], acc[i][1] + bs[1]);
      pk.y = pack2(acc[i][2] + bs[2], acc[i][3] + bs[3]);
      pk.z = pack2(acc[i][4] + bs[4], acc[i][5] + bs[5]);
      pk.w = pack2(acc[i][6] + bs[6], acc[i][7] + bs[7]);
      *(uint4*)&o16[row] = pk;
    }
  } else {
    float* out = (float*)outp;
#pragma unroll
    for (int i = 0; i < 4; ++i) {
      size_t row = (size_t)(mbase + m0 + i) * Ncols + nbase + n0;
      float4 r0 = make_float4(acc[i][0] + bs[0], acc[i][1] + bs[1],
                              acc[i][2] + bs[2], acc[i][3] + bs[3]);
      float4 r1 = make_float4(acc[i][4] + bs[4], acc[i][5] + bs[5],
                              acc[i][6] + bs[6], acc[i][7] + bs[7]);
      *(float4*)&out[row] = r0;
      *(float4*)&out[row + 4] = r1;
    }
  }
}

// ---------------- persistent recurrence ----------------
// 64 blocks (1/batch) x 256 threads (4 waves = 1 wave/SIMD -> full 512-VGPR budget).
// Thread t owns rows t and t+256: h_new[r] = tanh(xp[r] + dot(W_hh[r,:], h)).
// W row split: RG=42 quad-groups in VGPRs (336 regs), LG=18 in LDS (144KB),
// SG=4 streamed coalesced from L2 (wq is 512KB, L2-resident; 8 blocks/XCD share it).

#define DOT4(W, HH, A0, A1, A2, A3)               \
  { A0 = fdot2((W).x, (HH).x, A0);                \
    A1 = fdot2((W).y, (HH).y, A1);                \
    A2 = fdot2((W).z, (HH).z, A2);                \
    A3 = fdot2((W).w, (HH).w, A3); }

__global__ __attribute__((amdgpu_flat_work_group_size(256, 256),
                          amdgpu_waves_per_eu(1, 1)))
void k_rnn(
    const uint4* __restrict__ wq,     // [64][512] uint4 (k-group x output-row)
    const h16* __restrict__ xp,       // [B*S][H] f16
    const float* __restrict__ h0,     // [B][H] f32
    h16* __restrict__ hs)             // [B*S][H] f16
{
  __shared__ uint4 lwf[LG * H_];      // LDS-resident W groups: 144KB
  __shared__ uint4 hq[2][H_ / 8];     // double-buffered h (2 x 1KB)
  const int t = threadIdx.x;          // 0..255
  const int b = blockIdx.x;
  const int r1 = t + 256;

  uint4 wrA[RG], wrB[RG];
#pragma unroll
  for (int g = 0; g < RG; ++g) {
    wrA[g] = wq[(size_t)g * H_ + t];
    wrB[g] = wq[(size_t)g * H_ + r1];
  }
  for (int i = t; i < LG * H_; i += 256) lwf[i] = wq[(size_t)RG * H_ + i];
  ((unsigned short*)&hq[0][0])[t] =
      __builtin_bit_cast(unsigned short, (h16)h0[(size_t)b * H_ + t]);
  ((unsigned short*)&hq[0][0])[r1] =
      __builtin_bit_cast(unsigned short, (h16)h0[(size_t)b * H_ + r1]);

  const uint4* wqs = wq + (size_t)(RG + LG) * H_;   // stream groups
  const h16* xpb = xp + (size_t)b * S_ * H_;
  h16* hsb = hs + (size_t)b * S_ * H_;
  __syncthreads();

  for (int step = 0; step < S_; ++step) {
    const uint4* h4 = hq[step & 1];
    float xv0 = (float)xpb[(size_t)step * H_ + t];
    float xv1 = (float)xpb[(size_t)step * H_ + r1];
    float a0 = 0.f, a1 = 0.f, a2 = 0.f, a3 = 0.f;
    float c0 = 0.f, c1 = 0.f, c2 = 0.f, c3 = 0.f;
    uint4 sA[SG], sB[SG];
#pragma unroll
    for (int j = 0; j < SG; ++j) {        // issue L2 stream early (coalesced)
      sA[j] = wqs[(size_t)j * H_ + t];
      sB[j] = wqs[(size_t)j * H_ + r1];
    }
#pragma unroll
    for (int g = 0; g < RG; ++g) {        // register-resident W
      uint4 hv = h4[g];
      DOT4(wrA[g], hv, a0, a1, a2, a3);
      DOT4(wrB[g], hv, c0, c1, c2, c3);
    }
#pragma unroll
    for (int j = 0; j < LG; ++j) {        // LDS-resident W
      uint4 hv = h4[RG + j];
      uint4 w0 = lwf[j * H_ + t];
      uint4 w1 = lwf[j * H_ + r1];
      DOT4(w0, hv, a0, a1, a2, a3);
      DOT4(w1, hv, c0, c1, c2, c3);
    }
#pragma unroll
    for (int j = 0; j < SG; ++j) {        // consume stream
      uint4 hv = h4[RG + LG + j];
      DOT4(sA[j], hv, a0, a1, a2, a3);
      DOT4(sB[j], hv, c0, c1, c2, c3);
    }
    float hn0 = fast_tanh(((a0 + a1) + (a2 + a3)) + xv0);
    float hn1 = fast_tanh(((c0 + c1) + (c2 + c3)) + xv1);
    h16 h0_16 = (h16)hn0, h1_16 = (h16)hn1;
    unsigned short* nb = (unsigned short*)&hq[(step + 1) & 1][0];
    nb[t]  = __builtin_bit_cast(unsigned short, h0_16);
    nb[r1] = __builtin_bit_cast(unsigned short, h1_16);
    hsb[(size_t)step * H_ + t]  = h0_16;
    hsb[(size_t)step * H_ + r1] = h1_16;
    __syncthreads();   // next-buffer h visible; safe (reads of cur precede arrival)
  }
}

// ---------------- host launch ----------------

extern "C" void kernel_launch(void* const* d_in, const int* in_sizes, int n_in,
                              void* d_out, int out_size, void* d_ws, size_t ws_size,
                              hipStream_t stream) {
  (void)in_sizes; (void)n_in; (void)out_size; (void)ws_size;
  const float* x   = (const float*)d_in[0];
  const float* h0  = (const float*)d_in[1];
  const float* Wih = (const float*)d_in[2];
  const float* Whh = (const float*)d_in[3];
  const float* bih = (const float*)d_in[4];
  const float* bhh = (const float*)d_in[5];
  const float* Wff = (const float*)d_in[6];
  const float* bff = (const float*)d_in[7];
  float* out = (float*)d_out;

  char* ws = (char*)d_ws;
  size_t off = 0;
  h16* xp16 = (h16*)(ws + off);           off += (size_t)B_ * S_ * H_ * 2;        // 33.5 MB
  uint32_t* xpk = (uint32_t*)(ws + off);  off += (size_t)B_ * S_ * (IN_ / 2) * 4; // 16.8 MB
  h16* hs = (h16*)(ws + off);             off += (size_t)B_ * S_ * H_ * 2;        // 33.5 MB
  uint32_t* whq = (uint32_t*)(ws + off);  off += (size_t)64 * H_ * 16;            // 0.5 MB
  uint32_t* wihp = (uint32_t*)(ws + off); off += (size_t)(IN_ / 2) * H_ * 4;
  uint32_t* wffp = (uint32_t*)(ws + off); off += (size_t)(H_ / 2) * O_ * 4;

  k_pack_x<<<2048, 256, 0, stream>>>((const float2*)x, xpk, B_ * S_ * (IN_ / 2));
  k_pack_wih<<<256, 256, 0, stream>>>(Wih, wihp);
  k_pack_whh<<<512, 256, 0, stream>>>(Whh, whq);
  k_pack_wff<<<256, 256, 0, stream>>>(Wff, wffp);

  // xp = x @ W_ih^T + b_ih + b_hh   (M=32768, N=512, K=256) -> f16 packed
  k_gemm<2, true><<<dim3(256, 8), 256, 0, stream>>>(xpk, wihp, bih, bhh, xp16, H_);
  // recurrence
  k_rnn<<<64, 256, 0, stream>>>((const uint4*)whq, xp16, h0, hs);
  // out = hs @ W_ff^T + b_ff        (M=32768, N=256, K=512) -> f32
  k_gemm<4, false><<<dim3(256, 4), 256, 0, stream>>>((const uint32_t*)hs, wffp, bff, nullptr, out, O_);
}

// Round 4
// 1068.032 us; speedup vs baseline: 2.1256x; 2.1256x over previous
//
#include <hip/hip_runtime.h>
#include <hip/hip_bf16.h>
#include <stdint.h>

#define B_   64
#define S_   512
#define IN_  256
#define H_   512
#define O_   256

// k_rnn W_hh residency split (64 k-groups of 8 cols each):
//   RG quads in VGPRs (176 regs), LG in LDS (~82KB), SG streamed from L2.
// Pipes/step @512thr: VALU ~1024cy, LDS ~LG*96+256cy, L2-port ~SG*128cy.
#define RG 44
#define LG 10
#define SG 10

typedef _Float16 h16;
typedef __attribute__((ext_vector_type(2))) _Float16 half2v;

static __device__ __forceinline__ float fdot2(uint32_t w, uint32_t h, float acc) {
#if __has_builtin(__builtin_amdgcn_fdot2)
  return __builtin_amdgcn_fdot2(__builtin_bit_cast(half2v, w),
                                __builtin_bit_cast(half2v, h), acc, false);
#else
  half2v a = __builtin_bit_cast(half2v, w), b = __builtin_bit_cast(half2v, h);
  return acc + (float)a[0] * (float)b[0] + (float)a[1] * (float)b[1];
#endif
}

static __device__ __forceinline__ uint32_t pack2(float a, float b) {
  h16 lo = (h16)a, hi = (h16)b;
  uint32_t u = (uint32_t)__builtin_bit_cast(unsigned short, lo);
  uint32_t v = (uint32_t)__builtin_bit_cast(unsigned short, hi);
  return u | (v << 16);
}

static __device__ __forceinline__ float fast_tanh(float x) {
#if __has_builtin(__builtin_amdgcn_exp2f) && __has_builtin(__builtin_amdgcn_rcpf)
  float xc = fminf(9.0f, fmaxf(-9.0f, x));
  float e2 = __builtin_amdgcn_exp2f(xc * 2.8853900817779268f);  // e^{2x}
  return (e2 - 1.0f) * __builtin_amdgcn_rcpf(e2 + 1.0f);
#else
  return tanhf(x);
#endif
}

// ---------------- packing kernels (f32 -> f16x2 dwords) ----------------

__global__ void k_pack_x(const float2* __restrict__ x2, uint32_t* __restrict__ xpk, int n) {
  int i = blockIdx.x * blockDim.x + threadIdx.x;
  int stride = gridDim.x * blockDim.x;
  for (; i < n; i += stride) { float2 v = x2[i]; xpk[i] = pack2(v.x, v.y); }
}

// W_ih (H,IN) -> [k2][n] dwords
__global__ void k_pack_wih(const float* __restrict__ w, uint32_t* __restrict__ wp) {
  int i = blockIdx.x * 256 + threadIdx.x;   // 65536
  int k2 = i >> 9, n = i & 511;
  wp[i] = pack2(w[n * IN_ + 2 * k2], w[n * IN_ + 2 * k2 + 1]);
}

// W_ff (O,H) -> [k2][o] dwords
__global__ void k_pack_wff(const float* __restrict__ w, uint32_t* __restrict__ wp) {
  int i = blockIdx.x * 256 + threadIdx.x;   // 65536
  int k2 = i >> 8, o = i & 255;
  wp[i] = pack2(w[o * H_ + 2 * k2], w[o * H_ + 2 * k2 + 1]);
}

// W_hh (H,H) -> uint4 quads: [g][o], g=k/8 in [0,64), o in [0,512)
__global__ void k_pack_whh(const float* __restrict__ w, uint32_t* __restrict__ wp) {
  int i = blockIdx.x * 256 + threadIdx.x;   // 131072 dwords
  int g = i >> 11, o = (i >> 2) & 511, c = i & 3;
  int k = 8 * g + 2 * c;
  wp[i] = pack2(w[o * H_ + k], w[o * H_ + k + 1]);
}

// ---------------- tiled fdot2 GEMM:  out[M][N] = A[M][K] * W[N][K]^T + bias ----

template <int NSTAGES, bool OUT16>
__global__ void __launch_bounds__(256) k_gemm(
    const uint32_t* __restrict__ apack, const uint32_t* __restrict__ wpack,
    const float* __restrict__ bias0, const float* __restrict__ bias1,
    void* __restrict__ outp, int Ncols)
{
  const int K2 = NSTAGES * 64;
  __shared__ uint32_t xs[128][65];
  __shared__ uint32_t ws[64][64];
  const int tid = threadIdx.x;
  const int mbase = blockIdx.x * 128;
  const int nbase = blockIdx.y * 64;
  const int tx = tid & 7, ty = tid >> 3;
  const int m0 = ty * 4, n0 = tx * 8;

  float bs[8];
#pragma unroll
  for (int j = 0; j < 8; ++j) {
    int n = nbase + n0 + j;
    bs[j] = bias0[n] + (bias1 ? bias1[n] : 0.0f);
  }

  float acc[4][8];
#pragma unroll
  for (int i = 0; i < 4; ++i)
#pragma unroll
    for (int j = 0; j < 8; ++j) acc[i][j] = 0.0f;

  for (int s = 0; s < NSTAGES; ++s) {
    const int k2b = s * 64;
    __syncthreads();
#pragma unroll
    for (int c = 0; c < 32; ++c) {
      int idx = c * 256 + tid;
      int m = idx >> 6, k2 = idx & 63;
      xs[m][k2] = apack[(size_t)(mbase + m) * K2 + k2b + k2];
    }
#pragma unroll
    for (int c = 0; c < 16; ++c) {
      int idx = c * 256 + tid;
      int k2 = idx >> 6, n = idx & 63;
      ws[k2][n] = wpack[(size_t)(k2b + k2) * Ncols + nbase + n];
    }
    __syncthreads();
#pragma unroll 8
    for (int k2 = 0; k2 < 64; ++k2) {
      uint32_t xv[4];
#pragma unroll
      for (int i = 0; i < 4; ++i) xv[i] = xs[m0 + i][k2];
      uint4 wA = *(const uint4*)&ws[k2][n0];
      uint4 wB = *(const uint4*)&ws[k2][n0 + 4];
#pragma unroll
      for (int i = 0; i < 4; ++i) {
        acc[i][0] = fdot2(xv[i], wA.x, acc[i][0]);
        acc[i][1] = fdot2(xv[i], wA.y, acc[i][1]);
        acc[i][2] = fdot2(xv[i], wA.z, acc[i][2]);
        acc[i][3] = fdot2(xv[i], wA.w, acc[i][3]);
        acc[i][4] = fdot2(xv[i], wB.x, acc[i][4]);
        acc[i][5] = fdot2(xv[i], wB.y, acc[i][5]);
        acc[i][6] = fdot2(xv[i], wB.z, acc[i][6]);
        acc[i][7] = fdot2(xv[i], wB.w, acc[i][7]);
      }
    }
  }
  if constexpr (OUT16) {
    uint32_t* o16 = (uint32_t*)outp;
    const int ncd = Ncols >> 1;
#pragma unroll
    for (int i = 0; i < 4; ++i) {
      size_t row = (size_t)(mbase + m0 + i) * ncd + ((nbase + n0) >> 1);
      uint4 pk;
      pk.x = pack2(acc[i][0] + bs[0], acc[i][1] + bs[1]);
      pk.y = pack2(acc[i][2] + bs[2], acc[i][3] + bs[3]);
      pk.z = pack2(acc[i][4] + bs[4], acc[i][5] + bs[5]);
      pk.w = pack2(acc[i][6] + bs[6], acc[i][7] + bs[7]);
      *(uint4*)&o16[row] = pk;
    }
  } else {
    float* out = (float*)outp;
#pragma unroll
    for (int i = 0; i < 4; ++i) {
      size_t row = (size_t)(mbase + m0 + i) * Ncols + nbase + n0;
      float4 r0 = make_float4(acc[i][0] + bs[0], acc[i][1] + bs[1],
                              acc[i][2] + bs[2], acc[i][3] + bs[3]);
      float4 r1 = make_float4(acc[i][4] + bs[4], acc[i][5] + bs[5],
                              acc[i][6] + bs[6], acc[i][7] + bs[7]);
      *(float4*)&out[row] = r0;
      *(float4*)&out[row + 4] = r1;
    }
  }
}

// ---------------- persistent recurrence ----------------
// 64 blocks (1/batch) x 512 threads (8 waves = 2 waves/EU -> 256-VGPR cap).
// Thread t owns row t: h_new[t] = tanh(xp[t] + dot(W_hh[t,:], h)).
// W row: RG=44 quads in VGPRs (176 regs, fits 256 cap), LG=10 in LDS,
// SG=10 streamed from L2 in two 5-quad chunks (peak ~20 stream regs live).

#define DOT4(W, HH)                               \
  { acc0 = fdot2((W).x, (HH).x, acc0);            \
    acc1 = fdot2((W).y, (HH).y, acc1);            \
    acc2 = fdot2((W).z, (HH).z, acc2);            \
    acc3 = fdot2((W).w, (HH).w, acc3); }

__global__ __attribute__((amdgpu_flat_work_group_size(512, 512),
                          amdgpu_waves_per_eu(2, 2)))
void k_rnn(
    const uint4* __restrict__ wq,     // [64][512] uint4 (k-group x output-row)
    const h16* __restrict__ xp,       // [B*S][H] f16
    const float* __restrict__ h0,     // [B][H] f32
    h16* __restrict__ hs)             // [B*S][H] f16
{
  __shared__ uint4 lw[LG * H_];       // LDS-resident W groups: 80KB
  __shared__ uint4 hq[2][H_ / 8];     // double-buffered h (2 x 1KB)
  const int t = threadIdx.x;          // 0..511
  const int b = blockIdx.x;

  uint4 wr[RG];
#pragma unroll
  for (int g = 0; g < RG; ++g) wr[g] = wq[(size_t)g * H_ + t];
  for (int i = t; i < LG * H_; i += 512) lw[i] = wq[(size_t)RG * H_ + i];
  ((unsigned short*)&hq[0][0])[t] =
      __builtin_bit_cast(unsigned short, (h16)h0[(size_t)b * H_ + t]);

  const uint4* wqs = wq + (size_t)(RG + LG) * H_ + t;   // stream base
  const h16* xpb = xp + (size_t)b * S_ * H_ + t;
  h16* hsb = hs + (size_t)b * S_ * H_ + t;
  __syncthreads();

  for (int step = 0; step < S_; ++step) {
    const uint4* h4 = hq[step & 1];
    float xv = (float)xpb[(size_t)step * H_];            // early global load
    float acc0 = 0.f, acc1 = 0.f, acc2 = 0.f, acc3 = 0.f;
    uint4 sA[5], sB[5];
#pragma unroll
    for (int j = 0; j < 5; ++j) sA[j] = wqs[(size_t)j * H_];     // issue chunk A
#pragma unroll
    for (int g = 0; g < 22; ++g) DOT4(wr[g], h4[g]);             // cover latency
#pragma unroll
    for (int j = 0; j < 5; ++j) DOT4(sA[j], h4[RG + LG + j]);    // consume A
#pragma unroll
    for (int j = 0; j < 5; ++j) sB[j] = wqs[(size_t)(5 + j) * H_]; // issue chunk B
#pragma unroll
    for (int g = 22; g < RG; ++g) DOT4(wr[g], h4[g]);
#pragma unroll
    for (int j = 0; j < LG; ++j) { uint4 w = lw[j * H_ + t]; DOT4(w, h4[RG + j]); }
#pragma unroll
    for (int j = 0; j < 5; ++j) DOT4(sB[j], h4[RG + LG + 5 + j]); // consume B
    float hn = fast_tanh(((acc0 + acc1) + (acc2 + acc3)) + xv);
    h16 hn16 = (h16)hn;
    ((unsigned short*)&hq[(step + 1) & 1][0])[t] =
        __builtin_bit_cast(unsigned short, hn16);                 // next buffer
    hsb[(size_t)step * H_] = hn16;
    __syncthreads();                                              // next h ready
  }
}

// ---------------- host launch ----------------

extern "C" void kernel_launch(void* const* d_in, const int* in_sizes, int n_in,
                              void* d_out, int out_size, void* d_ws, size_t ws_size,
                              hipStream_t stream) {
  (void)in_sizes; (void)n_in; (void)out_size; (void)ws_size;
  const float* x   = (const float*)d_in[0];
  const float* h0  = (const float*)d_in[1];
  const float* Wih = (const float*)d_in[2];
  const float* Whh = (const float*)d_in[3];
  const float* bih = (const float*)d_in[4];
  const float* bhh = (const float*)d_in[5];
  const float* Wff = (const float*)d_in[6];
  const float* bff = (const float*)d_in[7];
  float* out = (float*)d_out;

  char* ws = (char*)d_ws;
  size_t off = 0;
  h16* xp16 = (h16*)(ws + off);           off += (size_t)B_ * S_ * H_ * 2;        // 33.5 MB
  uint32_t* xpk = (uint32_t*)(ws + off);  off += (size_t)B_ * S_ * (IN_ / 2) * 4; // 16.8 MB
  h16* hs = (h16*)(ws + off);             off += (size_t)B_ * S_ * H_ * 2;        // 33.5 MB
  uint32_t* whq = (uint32_t*)(ws + off);  off += (size_t)64 * H_ * 16;            // 0.5 MB
  uint32_t* wihp = (uint32_t*)(ws + off); off += (size_t)(IN_ / 2) * H_ * 4;
  uint32_t* wffp = (uint32_t*)(ws + off); off += (size_t)(H_ / 2) * O_ * 4;

  k_pack_x<<<2048, 256, 0, stream>>>((const float2*)x, xpk, B_ * S_ * (IN_ / 2));
  k_pack_wih<<<256, 256, 0, stream>>>(Wih, wihp);
  k_pack_whh<<<512, 256, 0, stream>>>(Whh, whq);
  k_pack_wff<<<256, 256, 0, stream>>>(Wff, wffp);

  // xp = x @ W_ih^T + b_ih + b_hh   (M=32768, N=512, K=256) -> f16 packed
  k_gemm<2, true><<<dim3(256, 8), 256, 0, stream>>>(xpk, wihp, bih, bhh, xp16, H_);
  // recurrence
  k_rnn<<<64, 512, 0, stream>>>((const uint4*)whq, xp16, h0, hs);
  // out = hs @ W_ff^T + b_ff        (M=32768, N=256, K=512) -> f32
  k_gemm<4, false><<<dim3(256, 4), 256, 0, stream>>>((const uint32_t*)hs, wffp, bff, nullptr, out, O_);
}